// Round 1
// baseline (1113.298 us; speedup 1.0000x reference)
//
#include <hip/hip_runtime.h>
#include <math.h>

#define N_NODES 100000
#define D 128
#define N_EDGES 1600000
#define BN_EPS 1e-5f

// ---------------- BN column stats: sum and sumsq per column ----------------
__global__ __launch_bounds__(256)
void bn_stats(const float* __restrict__ x, float* __restrict__ sums) {
    const int col  = threadIdx.x & 127;
    const int half = threadIdx.x >> 7;
    float s = 0.f, sq = 0.f;
    for (int r = blockIdx.x * 2 + half; r < N_NODES; r += gridDim.x * 2) {
        float v = x[(size_t)r * D + col];
        s += v; sq += v * v;
    }
    __shared__ float ls[2][128];
    __shared__ float lq[2][128];
    ls[half][col] = s; lq[half][col] = sq;
    __syncthreads();
    if (threadIdx.x < 128) {
        atomicAdd(&sums[col],       ls[0][col] + ls[1][col]);
        atomicAdd(&sums[128 + col], lq[0][col] + lq[1][col]);
    }
}

// ---------------- fold BN into per-column scale/bias ----------------
__global__ void bn_finalize(const float* __restrict__ sums,
                            const float* __restrict__ gamma,
                            const float* __restrict__ beta,
                            float* __restrict__ scale, float* __restrict__ bias) {
    int c = threadIdx.x;
    float mean = sums[c] * (1.0f / N_NODES);
    float var  = sums[128 + c] * (1.0f / N_NODES) - mean * mean;
    float rstd = rsqrtf(var + BN_EPS);
    float sc = gamma[c] * rstd;
    scale[c] = sc;
    bias[c]  = beta[c] - mean * sc;
}

// ---------------- fused: xn = BN(x); mapped = xn@K0; s1/s2 = tanh(xn@K{1,2} . xn) ----
__global__ __launch_bounds__(128)
void gemm_fused(const float* __restrict__ x,
                const float* __restrict__ k0, const float* __restrict__ k1,
                const float* __restrict__ k2,
                const float* __restrict__ scale, const float* __restrict__ bias,
                float* __restrict__ mapped, float* __restrict__ s1, float* __restrict__ s2) {
    const int c = threadIdx.x;
    const int base = blockIdx.x * 8;   // 100000 / 8 = 12500 blocks, exact
    __shared__ float xn[8][128];
    float sc = scale[c], bs = bias[c];
#pragma unroll
    for (int r = 0; r < 8; ++r)
        xn[r][c] = x[(size_t)(base + r) * D + c] * sc + bs;
    __syncthreads();

    float a0[8], a1[8], a2[8];
#pragma unroll
    for (int r = 0; r < 8; ++r) { a0[r] = 0.f; a1[r] = 0.f; a2[r] = 0.f; }

    for (int k = 0; k < 128; ++k) {
        float w0 = k0[k * 128 + c];
        float w1 = k1[k * 128 + c];
        float w2 = k2[k * 128 + c];
#pragma unroll
        for (int r = 0; r < 8; ++r) {
            float xk = xn[r][k];
            a0[r] = fmaf(xk, w0, a0[r]);
            a1[r] = fmaf(xk, w1, a1[r]);
            a2[r] = fmaf(xk, w2, a2[r]);
        }
    }
#pragma unroll
    for (int r = 0; r < 8; ++r)
        mapped[(size_t)(base + r) * D + c] = a0[r];

    // reductions for s1/s2
    __shared__ float red[2][2];
    const int lane = c & 63, wave = c >> 6;
#pragma unroll
    for (int r = 0; r < 8; ++r) {
        float xc = xn[r][c];
        float v1 = a1[r] * xc;
        float v2 = a2[r] * xc;
        for (int off = 32; off; off >>= 1) {
            v1 += __shfl_down(v1, off);
            v2 += __shfl_down(v2, off);
        }
        if (lane == 0) { red[wave][0] = v1; red[wave][1] = v2; }
        __syncthreads();
        if (c == 0) {
            s1[base + r] = tanhf(red[0][0] + red[1][0]);
            s2[base + r] = tanhf(red[0][1] + red[1][1]);
        }
        __syncthreads();
    }
}

// ---------------- init emax/denom ----------------
__global__ void init_nodes(float* __restrict__ emax, float* __restrict__ denom) {
    int i = blockIdx.x * 256 + threadIdx.x;
    if (i < N_NODES) { emax[i] = -INFINITY; denom[i] = 0.f; }
}

// ---------------- edge pass 1: e = leaky_relu(s1[src]+s2[dst]); segment max ---------
__global__ __launch_bounds__(256)
void edge_max(const int* __restrict__ src, const int* __restrict__ dst,
              const float* __restrict__ s1, const float* __restrict__ s2,
              float* __restrict__ e_buf, float* __restrict__ emax) {
    int i = blockIdx.x * 256 + threadIdx.x;
    if (i >= N_EDGES) return;
    int s = src[i], d = dst[i];
    float v = s1[s] + s2[d];
    float e = v > 0.f ? v : 0.01f * v;
    e_buf[i] = e;
    if (e >= 0.f) atomicMax((int*)&emax[s], __float_as_int(e));
    else          atomicMin((unsigned int*)&emax[s], __float_as_uint(e));
}

// ---------------- edge pass 2: ee = exp(e - emax[src]); segment sum ----------------
__global__ __launch_bounds__(256)
void edge_exp(const int* __restrict__ src, float* __restrict__ e_buf,
              const float* __restrict__ emax, float* __restrict__ denom) {
    int i = blockIdx.x * 256 + threadIdx.x;
    if (i >= N_EDGES) return;
    int s = src[i];
    float ee = expf(e_buf[i] - emax[s]);
    e_buf[i] = ee;
    atomicAdd(&denom[s], ee);
}

// ---------------- edge pass 3: out[src] += attn * mapped[dst] ----------------
__global__ __launch_bounds__(256)
void edge_aggregate(const int* __restrict__ src, const int* __restrict__ dst,
                    const float* __restrict__ e_buf, const float* __restrict__ denom,
                    const float* __restrict__ mapped, float* __restrict__ out) {
    int i = blockIdx.x * 2 + (threadIdx.x >> 7);
    int c = threadIdx.x & 127;
    if (i >= N_EDGES) return;
    int s = src[i], d = dst[i];
    float attn = e_buf[i] / fmaxf(denom[s], 1e-16f);
    atomicAdd(&out[(size_t)s * D + c], attn * mapped[(size_t)d * D + c]);
}

// ---------------- final relu ----------------
__global__ __launch_bounds__(256)
void relu_kernel(float* __restrict__ out) {
    size_t i = (size_t)blockIdx.x * 256 + threadIdx.x;
    if (i < (size_t)N_NODES * D) out[i] = fmaxf(out[i], 0.f);
}

extern "C" void kernel_launch(void* const* d_in, const int* in_sizes, int n_in,
                              void* d_out, int out_size, void* d_ws, size_t ws_size,
                              hipStream_t stream) {
    const float* x     = (const float*)d_in[0];
    const int*   ei    = (const int*)d_in[1];   // [2][E]: row0 = src, row1 = dst
    const float* k0    = (const float*)d_in[2];
    const float* k1    = (const float*)d_in[3];
    const float* k2    = (const float*)d_in[4];
    const float* gamma = (const float*)d_in[5];
    const float* beta  = (const float*)d_in[6];
    float* out = (float*)d_out;

    const int* src = ei;
    const int* dst = ei + N_EDGES;

    float* ws    = (float*)d_ws;
    float* s1    = ws;                      // N
    float* s2    = s1 + N_NODES;            // N
    float* emax  = s2 + N_NODES;            // N
    float* denom = emax + N_NODES;          // N
    float* scale = denom + N_NODES;         // 128
    float* bias  = scale + 128;             // 128
    float* sums  = bias + 128;              // 256
    float* e_buf = sums + 256;              // E
    float* mapped = e_buf + N_EDGES;        // N*D  (51.2 MB)

    // zero accumulators (harness does not re-poison between replays)
    hipMemsetAsync(sums, 0, 256 * sizeof(float), stream);
    hipMemsetAsync(out, 0, (size_t)N_NODES * D * sizeof(float), stream);

    bn_stats<<<256, 256, 0, stream>>>(x, sums);
    bn_finalize<<<1, 128, 0, stream>>>(sums, gamma, beta, scale, bias);
    gemm_fused<<<N_NODES / 8, 128, 0, stream>>>(x, k0, k1, k2, scale, bias,
                                                mapped, s1, s2);
    init_nodes<<<(N_NODES + 255) / 256, 256, 0, stream>>>(emax, denom);
    edge_max<<<N_EDGES / 256, 256, 0, stream>>>(src, dst, s1, s2, e_buf, emax);
    edge_exp<<<N_EDGES / 256, 256, 0, stream>>>(src, e_buf, emax, denom);
    edge_aggregate<<<N_EDGES / 2, 256, 0, stream>>>(src, dst, e_buf, denom,
                                                    mapped, out);
    relu_kernel<<<(N_NODES * D) / 256, 256, 0, stream>>>(out);
}

// Round 2
// 765.867 us; speedup vs baseline: 1.4536x; 1.4536x over previous
//
#include <hip/hip_runtime.h>
#include <math.h>

#define N_NODES 100000
#define D 128
#define N_EDGES 1600000
#define BN_EPS 1e-5f
#define SCAN_THREADS 1024
#define SCAN_CHUNK 98   // ceil(100000/1024)

// ---------------- BN column stats: sum and sumsq per column ----------------
__global__ __launch_bounds__(256)
void bn_stats(const float* __restrict__ x, float* __restrict__ sums) {
    const int col  = threadIdx.x & 127;
    const int half = threadIdx.x >> 7;
    float s = 0.f, sq = 0.f;
    for (int r = blockIdx.x * 2 + half; r < N_NODES; r += gridDim.x * 2) {
        float v = x[(size_t)r * D + col];
        s += v; sq += v * v;
    }
    __shared__ float ls[2][128];
    __shared__ float lq[2][128];
    ls[half][col] = s; lq[half][col] = sq;
    __syncthreads();
    if (threadIdx.x < 128) {
        atomicAdd(&sums[col],       ls[0][col] + ls[1][col]);
        atomicAdd(&sums[128 + col], lq[0][col] + lq[1][col]);
    }
}

// ---------------- fold BN into per-column scale/bias ----------------
__global__ void bn_finalize(const float* __restrict__ sums,
                            const float* __restrict__ gamma,
                            const float* __restrict__ beta,
                            float* __restrict__ scale, float* __restrict__ bias) {
    int c = threadIdx.x;
    float mean = sums[c] * (1.0f / N_NODES);
    float var  = sums[128 + c] * (1.0f / N_NODES) - mean * mean;
    float rstd = rsqrtf(var + BN_EPS);
    float sc = gamma[c] * rstd;
    scale[c] = sc;
    bias[c]  = beta[c] - mean * sc;
}

// ---------------- fused: xn = BN(x); mapped = xn@K0; s1/s2 = tanh(xn@K{1,2} . xn) ----
__global__ __launch_bounds__(128)
void gemm_fused(const float* __restrict__ x,
                const float* __restrict__ k0, const float* __restrict__ k1,
                const float* __restrict__ k2,
                const float* __restrict__ scale, const float* __restrict__ bias,
                float* __restrict__ mapped, float* __restrict__ s1, float* __restrict__ s2) {
    const int c = threadIdx.x;
    const int base = blockIdx.x * 8;   // 100000 / 8 = 12500 blocks, exact
    __shared__ float xn[8][128];
    float sc = scale[c], bs = bias[c];
#pragma unroll
    for (int r = 0; r < 8; ++r)
        xn[r][c] = x[(size_t)(base + r) * D + c] * sc + bs;
    __syncthreads();

    float a0[8], a1[8], a2[8];
#pragma unroll
    for (int r = 0; r < 8; ++r) { a0[r] = 0.f; a1[r] = 0.f; a2[r] = 0.f; }

    for (int k = 0; k < 128; ++k) {
        float w0 = k0[k * 128 + c];
        float w1 = k1[k * 128 + c];
        float w2 = k2[k * 128 + c];
#pragma unroll
        for (int r = 0; r < 8; ++r) {
            float xk = xn[r][k];
            a0[r] = fmaf(xk, w0, a0[r]);
            a1[r] = fmaf(xk, w1, a1[r]);
            a2[r] = fmaf(xk, w2, a2[r]);
        }
    }
#pragma unroll
    for (int r = 0; r < 8; ++r)
        mapped[(size_t)(base + r) * D + c] = a0[r];

    // reductions for s1/s2
    __shared__ float red[2][2];
    const int lane = c & 63, wave = c >> 6;
#pragma unroll
    for (int r = 0; r < 8; ++r) {
        float xc = xn[r][c];
        float v1 = a1[r] * xc;
        float v2 = a2[r] * xc;
        for (int off = 32; off; off >>= 1) {
            v1 += __shfl_down(v1, off);
            v2 += __shfl_down(v2, off);
        }
        if (lane == 0) { red[wave][0] = v1; red[wave][1] = v2; }
        __syncthreads();
        if (c == 0) {
            s1[base + r] = tanhf(red[0][0] + red[1][0]);
            s2[base + r] = tanhf(red[0][1] + red[1][1]);
        }
        __syncthreads();
    }
}

// ---------------- CSR build step 1: degree histogram (into cursor) ----------------
__global__ __launch_bounds__(256)
void degree_hist(const int* __restrict__ src, int* __restrict__ cursor) {
    int i = blockIdx.x * 256 + threadIdx.x;
    if (i < N_EDGES) atomicAdd(&cursor[src[i]], 1);
}

// ---------------- CSR build step 2: exclusive scan -> row_off; cursor := row_off ----
__global__ __launch_bounds__(SCAN_THREADS)
void scan_offsets(int* __restrict__ cursor, int* __restrict__ row_off) {
    __shared__ int tsum[SCAN_THREADS];
    const int t = threadIdx.x;
    const int lo = t * SCAN_CHUNK;
    const int hi = min(lo + SCAN_CHUNK, N_NODES);
    int s = 0;
    for (int i = lo; i < hi; ++i) s += cursor[i];
    tsum[t] = s;
    __syncthreads();
    // Hillis-Steele inclusive scan over thread totals
    for (int off = 1; off < SCAN_THREADS; off <<= 1) {
        int v = (t >= off) ? tsum[t - off] : 0;
        __syncthreads();
        tsum[t] += v;
        __syncthreads();
    }
    int run = (t == 0) ? 0 : tsum[t - 1];
    for (int i = lo; i < hi; ++i) {
        int d = cursor[i];
        row_off[i] = run;
        cursor[i]  = run;   // scatter cursor starts at segment base
        run += d;
    }
    if (t == SCAN_THREADS - 1) row_off[N_NODES] = tsum[SCAN_THREADS - 1];
}

// ---------------- CSR build step 3: scatter edges + compute leaky_relu score -------
__global__ __launch_bounds__(256)
void scatter_edges(const int* __restrict__ src, const int* __restrict__ dst,
                   const float* __restrict__ s1, const float* __restrict__ s2,
                   int* __restrict__ cursor,
                   int* __restrict__ dst_sorted, float* __restrict__ e_sorted) {
    int i = blockIdx.x * 256 + threadIdx.x;
    if (i >= N_EDGES) return;
    int s = src[i], d = dst[i];
    float v = s1[s] + s2[d];
    float e = v > 0.f ? v : 0.01f * v;
    int pos = atomicAdd(&cursor[s], 1);
    dst_sorted[pos] = d;
    e_sorted[pos] = e;
}

// ---------------- per-node: softmax + weighted gather-accumulate + relu ------------
__global__ __launch_bounds__(128)
void node_aggregate(const int* __restrict__ row_off, const int* __restrict__ dst_sorted,
                    const float* __restrict__ e_sorted, const float* __restrict__ mapped,
                    float* __restrict__ out) {
    const int n = blockIdx.x;
    const int c = threadIdx.x;
    const int beg = row_off[n], end = row_off[n + 1];
    float acc = 0.f;
    if (beg < end) {
        float m = -INFINITY;
        for (int j = beg; j < end; ++j) m = fmaxf(m, e_sorted[j]);  // broadcast loads
        float den = 0.f;
        __shared__ float ee[128];
        __shared__ int   dd[128];
        for (int chunk = beg; chunk < end; chunk += 128) {
            int nc = min(128, end - chunk);
            if (c < nc) {
                ee[c] = expf(e_sorted[chunk + c] - m);
                dd[c] = dst_sorted[chunk + c];
            }
            __syncthreads();
            for (int j = 0; j < nc; ++j) {
                float w = ee[j];
                den += w;
                acc = fmaf(w, mapped[(size_t)dd[j] * D + c], acc);
            }
            __syncthreads();
        }
        acc = acc / fmaxf(den, 1e-16f);
    }
    out[(size_t)n * D + c] = fmaxf(acc, 0.f);
}

extern "C" void kernel_launch(void* const* d_in, const int* in_sizes, int n_in,
                              void* d_out, int out_size, void* d_ws, size_t ws_size,
                              hipStream_t stream) {
    const float* x     = (const float*)d_in[0];
    const int*   ei    = (const int*)d_in[1];   // [2][E]: row0 = src, row1 = dst
    const float* k0    = (const float*)d_in[2];
    const float* k1    = (const float*)d_in[3];
    const float* k2    = (const float*)d_in[4];
    const float* gamma = (const float*)d_in[5];
    const float* beta  = (const float*)d_in[6];
    float* out = (float*)d_out;

    const int* src = ei;
    const int* dst = ei + N_EDGES;

    char* ws = (char*)d_ws;
    float* s1       = (float*)ws;                          ws += N_NODES * 4;
    float* s2       = (float*)ws;                          ws += N_NODES * 4;
    float* scale    = (float*)ws;                          ws += 128 * 4;
    float* bias     = (float*)ws;                          ws += 128 * 4;
    float* sums     = (float*)ws;                          ws += 256 * 4;
    int*   row_off  = (int*)ws;                            ws += (N_NODES + 1) * 4;
    int*   cursor   = (int*)ws;                            ws += N_NODES * 4;
    int*   dst_sorted = (int*)ws;                          ws += (size_t)N_EDGES * 4;
    float* e_sorted   = (float*)ws;                        ws += (size_t)N_EDGES * 4;
    float* mapped     = (float*)ws;                        ws += (size_t)N_NODES * D * 4;

    // zero accumulators (harness does not re-poison between replays)
    hipMemsetAsync(sums, 0, 256 * sizeof(float), stream);
    hipMemsetAsync(cursor, 0, N_NODES * sizeof(int), stream);

    bn_stats<<<256, 256, 0, stream>>>(x, sums);
    bn_finalize<<<1, 128, 0, stream>>>(sums, gamma, beta, scale, bias);
    gemm_fused<<<N_NODES / 8, 128, 0, stream>>>(x, k0, k1, k2, scale, bias,
                                                mapped, s1, s2);
    degree_hist<<<N_EDGES / 256, 256, 0, stream>>>(src, cursor);
    scan_offsets<<<1, SCAN_THREADS, 0, stream>>>(cursor, row_off);
    scatter_edges<<<N_EDGES / 256, 256, 0, stream>>>(src, dst, s1, s2, cursor,
                                                     dst_sorted, e_sorted);
    node_aggregate<<<N_NODES, 128, 0, stream>>>(row_off, dst_sorted, e_sorted,
                                                mapped, out);
}

// Round 3
// 543.987 us; speedup vs baseline: 2.0466x; 1.4079x over previous
//
#include <hip/hip_runtime.h>
#include <math.h>

#define N_NODES 100000
#define D 128
#define N_EDGES 1600000
#define BN_EPS 1e-5f
#define SCAN_NB 200
#define SCAN_BC 500   // elements per scan block; 200*500 = 100000 exact

// ---------------- BN column stats: sum and sumsq per column ----------------
__global__ __launch_bounds__(256)
void bn_stats(const float* __restrict__ x, float* __restrict__ sums) {
    const int col  = threadIdx.x & 127;
    const int half = threadIdx.x >> 7;
    float s = 0.f, sq = 0.f;
    for (int r = blockIdx.x * 2 + half; r < N_NODES; r += gridDim.x * 2) {
        float v = x[(size_t)r * D + col];
        s += v; sq += v * v;
    }
    __shared__ float ls[2][128];
    __shared__ float lq[2][128];
    ls[half][col] = s; lq[half][col] = sq;
    __syncthreads();
    if (threadIdx.x < 128) {
        atomicAdd(&sums[col],       ls[0][col] + ls[1][col]);
        atomicAdd(&sums[128 + col], lq[0][col] + lq[1][col]);
    }
}

// ---------------- fold BN into per-column scale/bias ----------------
__global__ void bn_finalize(const float* __restrict__ sums,
                            const float* __restrict__ gamma,
                            const float* __restrict__ beta,
                            float* __restrict__ scale, float* __restrict__ bias) {
    int c = threadIdx.x;
    float mean = sums[c] * (1.0f / N_NODES);
    float var  = sums[128 + c] * (1.0f / N_NODES) - mean * mean;
    float rstd = rsqrtf(var + BN_EPS);
    float sc = gamma[c] * rstd;
    scale[c] = sc;
    bias[c]  = beta[c] - mean * sc;
}

// ---------------- fused: xn = BN(x); mapped = xn@K0; s1/s2 = tanh(xn@K{1,2} . xn) ----
__global__ __launch_bounds__(128)
void gemm_fused(const float* __restrict__ x,
                const float* __restrict__ k0, const float* __restrict__ k1,
                const float* __restrict__ k2,
                const float* __restrict__ scale, const float* __restrict__ bias,
                float* __restrict__ mapped, float* __restrict__ s1, float* __restrict__ s2) {
    const int c = threadIdx.x;
    const int base = blockIdx.x * 8;   // 100000 / 8 = 12500 blocks, exact
    __shared__ float xn[8][128];
    float sc = scale[c], bs = bias[c];
#pragma unroll
    for (int r = 0; r < 8; ++r)
        xn[r][c] = x[(size_t)(base + r) * D + c] * sc + bs;
    __syncthreads();

    float a0[8], a1[8], a2[8];
#pragma unroll
    for (int r = 0; r < 8; ++r) { a0[r] = 0.f; a1[r] = 0.f; a2[r] = 0.f; }

    for (int k = 0; k < 128; ++k) {
        float w0 = k0[k * 128 + c];
        float w1 = k1[k * 128 + c];
        float w2 = k2[k * 128 + c];
#pragma unroll
        for (int r = 0; r < 8; ++r) {
            float xk = xn[r][k];
            a0[r] = fmaf(xk, w0, a0[r]);
            a1[r] = fmaf(xk, w1, a1[r]);
            a2[r] = fmaf(xk, w2, a2[r]);
        }
    }
#pragma unroll
    for (int r = 0; r < 8; ++r)
        mapped[(size_t)(base + r) * D + c] = a0[r];

    // reductions for s1/s2
    __shared__ float red[2][2];
    const int lane = c & 63, wave = c >> 6;
#pragma unroll
    for (int r = 0; r < 8; ++r) {
        float xc = xn[r][c];
        float v1 = a1[r] * xc;
        float v2 = a2[r] * xc;
        for (int off = 32; off; off >>= 1) {
            v1 += __shfl_down(v1, off);
            v2 += __shfl_down(v2, off);
        }
        if (lane == 0) { red[wave][0] = v1; red[wave][1] = v2; }
        __syncthreads();
        if (c == 0) {
            s1[base + r] = tanhf(red[0][0] + red[1][0]);
            s2[base + r] = tanhf(red[0][1] + red[1][1]);
        }
        __syncthreads();
    }
}

// ---------------- CSR build step 1: degree histogram (into cursor) ----------------
__global__ __launch_bounds__(256)
void degree_hist(const int* __restrict__ src, int* __restrict__ cursor) {
    int i = blockIdx.x * 256 + threadIdx.x;
    if (i < N_EDGES) atomicAdd(&cursor[src[i]], 1);
}

// ---------------- hierarchical scan, phase A: per-block sums ----------------
__global__ __launch_bounds__(256)
void scan_blocksum(const int* __restrict__ cursor, int* __restrict__ bsum) {
    __shared__ int red[256];
    const int b = blockIdx.x, t = threadIdx.x;
    const int base = b * SCAN_BC;
    int s = 0;
    for (int i = t; i < SCAN_BC; i += 256) s += cursor[base + i];
    red[t] = s;
    __syncthreads();
    for (int off = 128; off; off >>= 1) {
        if (t < off) red[t] += red[t + off];
        __syncthreads();
    }
    if (t == 0) bsum[b] = red[0];
}

// ---------------- phase B: exclusive scan of the 200 block sums ----------------
__global__ __launch_bounds__(256)
void scan_bases(int* __restrict__ bsum, int* __restrict__ row_off) {
    __shared__ int v[256];
    const int t = threadIdx.x;
    v[t] = (t < SCAN_NB) ? bsum[t] : 0;
    __syncthreads();
    for (int off = 1; off < 256; off <<= 1) {
        int u = (t >= off) ? v[t - off] : 0;
        __syncthreads();
        v[t] += u;
        __syncthreads();
    }
    if (t < SCAN_NB) bsum[t] = (t == 0) ? 0 : v[t - 1];
    if (t == 0) row_off[N_NODES] = v[SCAN_NB - 1];
}

// ---------------- phase C: per-block exclusive scan + write row_off/cursor ---------
__global__ __launch_bounds__(256)
void scan_write(int* __restrict__ cursor, const int* __restrict__ bsum,
                int* __restrict__ row_off) {
    __shared__ int tsum[256];
    const int b = blockIdx.x, t = threadIdx.x;
    const int i0 = b * SCAN_BC + t * 2;   // t < 250 covers the 500-elem chunk
    int d0 = 0, d1 = 0;
    if (t < 250) { d0 = cursor[i0]; d1 = cursor[i0 + 1]; }
    tsum[t] = d0 + d1;
    __syncthreads();
    for (int off = 1; off < 256; off <<= 1) {
        int u = (t >= off) ? tsum[t - off] : 0;
        __syncthreads();
        tsum[t] += u;
        __syncthreads();
    }
    if (t < 250) {
        int run = bsum[b] + ((t == 0) ? 0 : tsum[t - 1]);
        row_off[i0] = run; cursor[i0] = run; run += d0;
        row_off[i0 + 1] = run; cursor[i0 + 1] = run;
    }
}

// ---------------- CSR build step 3: scatter edges + compute leaky_relu score -------
__global__ __launch_bounds__(256)
void scatter_edges(const int* __restrict__ src, const int* __restrict__ dst,
                   const float* __restrict__ s1, const float* __restrict__ s2,
                   int* __restrict__ cursor,
                   int* __restrict__ dst_sorted, float* __restrict__ e_sorted) {
    int i = blockIdx.x * 256 + threadIdx.x;
    if (i >= N_EDGES) return;
    int s = src[i], d = dst[i];
    float v = s1[s] + s2[d];
    float e = v > 0.f ? v : 0.01f * v;
    int pos = atomicAdd(&cursor[s], 1);
    dst_sorted[pos] = d;
    e_sorted[pos] = e;
}

// ---------------- per-node: softmax + weighted gather-accumulate + relu ------------
__global__ __launch_bounds__(128)
void node_aggregate(const int* __restrict__ row_off, const int* __restrict__ dst_sorted,
                    const float* __restrict__ e_sorted, const float* __restrict__ mapped,
                    float* __restrict__ out) {
    const int n = blockIdx.x;
    const int c = threadIdx.x;
    const int beg = row_off[n], end = row_off[n + 1];
    float acc = 0.f;
    if (beg < end) {
        float m = -INFINITY;
        for (int j = beg; j < end; ++j) m = fmaxf(m, e_sorted[j]);  // broadcast loads
        float den = 0.f;
        __shared__ float ee[128];
        __shared__ int   dd[128];
        for (int chunk = beg; chunk < end; chunk += 128) {
            int nc = min(128, end - chunk);
            if (c < nc) {
                ee[c] = expf(e_sorted[chunk + c] - m);
                dd[c] = dst_sorted[chunk + c];
            }
            __syncthreads();
            for (int j = 0; j < nc; ++j) {
                float w = ee[j];
                den += w;
                acc = fmaf(w, mapped[(size_t)dd[j] * D + c], acc);
            }
            __syncthreads();
        }
        acc = acc / fmaxf(den, 1e-16f);
    }
    out[(size_t)n * D + c] = fmaxf(acc, 0.f);
}

extern "C" void kernel_launch(void* const* d_in, const int* in_sizes, int n_in,
                              void* d_out, int out_size, void* d_ws, size_t ws_size,
                              hipStream_t stream) {
    const float* x     = (const float*)d_in[0];
    const int*   ei    = (const int*)d_in[1];   // [2][E]: row0 = src, row1 = dst
    const float* k0    = (const float*)d_in[2];
    const float* k1    = (const float*)d_in[3];
    const float* k2    = (const float*)d_in[4];
    const float* gamma = (const float*)d_in[5];
    const float* beta  = (const float*)d_in[6];
    float* out = (float*)d_out;

    const int* src = ei;
    const int* dst = ei + N_EDGES;

    char* ws = (char*)d_ws;
    float* s1       = (float*)ws;                          ws += N_NODES * 4;
    float* s2       = (float*)ws;                          ws += N_NODES * 4;
    float* scale    = (float*)ws;                          ws += 128 * 4;
    float* bias     = (float*)ws;                          ws += 128 * 4;
    float* sums     = (float*)ws;                          ws += 256 * 4;
    int*   bsum     = (int*)ws;                            ws += 256 * 4;
    int*   row_off  = (int*)ws;                            ws += (N_NODES + 1) * 4;
    int*   cursor   = (int*)ws;                            ws += N_NODES * 4;
    int*   dst_sorted = (int*)ws;                          ws += (size_t)N_EDGES * 4;
    float* e_sorted   = (float*)ws;                        ws += (size_t)N_EDGES * 4;
    float* mapped     = (float*)ws;                        ws += (size_t)N_NODES * D * 4;

    // zero accumulators (harness does not re-poison between replays)
    hipMemsetAsync(sums, 0, 256 * sizeof(float), stream);
    hipMemsetAsync(cursor, 0, N_NODES * sizeof(int), stream);

    bn_stats<<<256, 256, 0, stream>>>(x, sums);
    bn_finalize<<<1, 128, 0, stream>>>(sums, gamma, beta, scale, bias);
    gemm_fused<<<N_NODES / 8, 128, 0, stream>>>(x, k0, k1, k2, scale, bias,
                                                mapped, s1, s2);
    degree_hist<<<N_EDGES / 256, 256, 0, stream>>>(src, cursor);
    scan_blocksum<<<SCAN_NB, 256, 0, stream>>>(cursor, bsum);
    scan_bases<<<1, 256, 0, stream>>>(bsum, row_off);
    scan_write<<<SCAN_NB, 256, 0, stream>>>(cursor, bsum, row_off);
    scatter_edges<<<N_EDGES / 256, 256, 0, stream>>>(src, dst, s1, s2, cursor,
                                                     dst_sorted, e_sorted);
    node_aggregate<<<N_NODES, 128, 0, stream>>>(row_off, dst_sorted, e_sorted,
                                                mapped, out);
}

// Round 5
// 476.349 us; speedup vs baseline: 2.3371x; 1.1420x over previous
//
#include <hip/hip_runtime.h>
#include <math.h>

#define N_NODES 100000
#define D 128
#define N_EDGES 1600000
#define BN_EPS 1e-5f
#define SCAN_NB 200
#define SCAN_BC 500   // elements per scan block; 200*500 = 100000 exact

typedef __attribute__((ext_vector_type(8))) short bf16x8;
typedef __attribute__((ext_vector_type(4))) float f32x4;

__device__ inline unsigned short f2bf(float f) {
    unsigned int u = __float_as_uint(f);
    unsigned int r = u + 0x7FFFu + ((u >> 16) & 1u);
    return (unsigned short)(r >> 16);
}
__device__ inline float bf2f(unsigned short b) {
    return __uint_as_float(((unsigned int)b) << 16);
}

// ---------------- BN column stats: sum and sumsq per column ----------------
__global__ __launch_bounds__(256)
void bn_stats(const float* __restrict__ x, float* __restrict__ sums) {
    const int col  = threadIdx.x & 127;
    const int half = threadIdx.x >> 7;
    float s = 0.f, sq = 0.f;
    for (int r = blockIdx.x * 2 + half; r < N_NODES; r += gridDim.x * 2) {
        float v = x[(size_t)r * D + col];
        s += v; sq += v * v;
    }
    __shared__ float ls[2][128];
    __shared__ float lq[2][128];
    ls[half][col] = s; lq[half][col] = sq;
    __syncthreads();
    if (threadIdx.x < 128) {
        atomicAdd(&sums[col],       ls[0][col] + ls[1][col]);
        atomicAdd(&sums[128 + col], lq[0][col] + lq[1][col]);
    }
}

// ---------------- fold BN into per-column scale/bias ----------------
__global__ void bn_finalize(const float* __restrict__ sums,
                            const float* __restrict__ gamma,
                            const float* __restrict__ beta,
                            float* __restrict__ scale, float* __restrict__ bias) {
    int c = threadIdx.x;
    float mean = sums[c] * (1.0f / N_NODES);
    float var  = sums[128 + c] * (1.0f / N_NODES) - mean * mean;
    float rstd = rsqrtf(var + BN_EPS);
    float sc = gamma[c] * rstd;
    scale[c] = sc;
    bias[c]  = beta[c] - mean * sc;
}

// ---------------- pack 3 weight matrices into bf16 B-fragment order (hi + lo) ------
// frag id = (m*32 + kk*8 + nt); element: k = kk*32 + (lane>>4)*8 + i, col = nt*16 + (lane&15)
// hi frags at [0, 6144), lo frags at [6144, 12288)
__global__ __launch_bounds__(256)
void pack_weights(const float* __restrict__ k0, const float* __restrict__ k1,
                  const float* __restrict__ k2, unsigned short* __restrict__ wpack) {
    int idx = blockIdx.x * 256 + threadIdx.x;     // one 8-elem fragment per thread
    if (idx >= 3 * 4 * 8 * 64) return;            // 6144
    int m    = idx >> 11;
    int r    = idx & 2047;
    int kk   = r >> 9;
    int r2   = r & 511;
    int nt   = r2 >> 6;
    int lane = r2 & 63;
    const float* W = (m == 0) ? k0 : (m == 1) ? k1 : k2;
    int col   = nt * 16 + (lane & 15);
    int kbase = kk * 32 + (lane >> 4) * 8;
    unsigned int wh[4], wl[4];
#pragma unroll
    for (int i = 0; i < 4; ++i) {
        float a = W[(kbase + 2 * i)     * 128 + col];
        float b = W[(kbase + 2 * i + 1) * 128 + col];
        unsigned short ah = f2bf(a), bh = f2bf(b);
        unsigned short al = f2bf(a - bf2f(ah)), bl = f2bf(b - bf2f(bh));
        wh[i] = (unsigned int)ah | ((unsigned int)bh << 16);
        wl[i] = (unsigned int)al | ((unsigned int)bl << 16);
    }
    uint4* outp = (uint4*)wpack;
    outp[idx]        = make_uint4(wh[0], wh[1], wh[2], wh[3]);
    outp[6144 + idx] = make_uint4(wl[0], wl[1], wl[2], wl[3]);
}

// ---------------- MFMA: xn = BN(x); mapped = xn@K0; s1/s2 = tanh((xn@K{1,2}).xn) ----
// mapped: plain bf16 (hi only). s1/s2: split-precision (hi+lo) to keep the
// quadratic form |z|~11 accurate to ~1e-4 (bf16-only gave z-err ~0.04 -> FAIL R4).
__global__ __launch_bounds__(256)
void gemm_mfma(const float* __restrict__ x, const unsigned short* __restrict__ wpack,
               const float* __restrict__ scale, const float* __restrict__ bias,
               float* __restrict__ mapped, float* __restrict__ s1, float* __restrict__ s2) {
    const int tid  = threadIdx.x;
    const int wave = tid >> 6, lane = tid & 63;
    const int base = blockIdx.x * 64;
    __shared__ unsigned short xhi[64 * 128];   // 16 KB bf16, XOR-swizzled rows
    __shared__ unsigned short xlo[64 * 128];   // 16 KB bf16 residual
    char* xbh = (char*)xhi;
    char* xbl = (char*)xlo;

    // ---- stage xn (BN applied) into LDS as bf16 hi+lo, swizzled ----
    float2 sc = ((const float2*)scale)[lane];
    float2 bs = ((const float2*)bias)[lane];
    for (int rr = 0; rr < 16; ++rr) {
        int row  = wave * 16 + rr;
        int node = base + row;
        float2 v = make_float2(0.f, 0.f);
        if (node < N_NODES) v = ((const float2*)x)[(size_t)node * 64 + lane];
        float f0 = v.x * sc.x + bs.x;
        float f1 = v.y * sc.y + bs.y;
        unsigned short h0 = f2bf(f0), h1 = f2bf(f1);
        unsigned short l0 = f2bf(f0 - bf2f(h0)), l1 = f2bf(f1 - bf2f(h1));
        int byte = (row * 256 + lane * 4) ^ ((row & 7) << 4);
        *(unsigned int*)(xbh + byte) = (unsigned int)h0 | ((unsigned int)h1 << 16);
        *(unsigned int*)(xbl + byte) = (unsigned int)l0 | ((unsigned int)l1 << 16);
    }
    __syncthreads();

    // ---- A fragments (row = lane&15, k = (lane>>4)*8 + i) ----
    bf16x8 ah[4], al[4];
    {
        int arow = wave * 16 + (lane & 15);
#pragma unroll
        for (int kk = 0; kk < 4; ++kk) {
            int byte = (arow * 256 + kk * 64 + (lane >> 4) * 16) ^ ((arow & 7) << 4);
            ah[kk] = *(const bf16x8*)(xbh + byte);
            al[kk] = *(const bf16x8*)(xbl + byte);
        }
    }
    const bf16x8* wp = (const bf16x8*)wpack;   // hi: [0,6144) frags; lo: +6144

    // ---- matrix 0 -> mapped (hi-only precision) ----
    {
        f32x4 acc[8] = {};
#pragma unroll
        for (int kk = 0; kk < 4; ++kk) {
#pragma unroll
            for (int nt = 0; nt < 8; ++nt) {
                bf16x8 b = wp[(kk * 8 + nt) * 64 + lane];
                acc[nt] = __builtin_amdgcn_mfma_f32_16x16x32_bf16(ah[kk], b, acc[nt], 0, 0, 0);
            }
        }
        int crow = base + wave * 16 + (lane >> 4) * 4;
        int ccol = lane & 15;
#pragma unroll
        for (int nt = 0; nt < 8; ++nt) {
#pragma unroll
            for (int reg = 0; reg < 4; ++reg) {
                int node = crow + reg;
                if (node < N_NODES)
                    mapped[(size_t)node * 128 + nt * 16 + ccol] = acc[nt][reg];
            }
        }
    }

    // ---- matrices 1,2 (split precision) -> per-row dot with xn -> s1,s2 ----
    {
        float p1[4] = {0.f, 0.f, 0.f, 0.f};
        float p2[4] = {0.f, 0.f, 0.f, 0.f};
        int lrow0 = wave * 16 + (lane >> 4) * 4;
#pragma unroll
        for (int nt = 0; nt < 8; ++nt) {
            f32x4 a1 = {0.f, 0.f, 0.f, 0.f};
            f32x4 a2 = {0.f, 0.f, 0.f, 0.f};
#pragma unroll
            for (int kk = 0; kk < 4; ++kk) {
                int fi = (kk * 8 + nt) * 64 + lane;
                bf16x8 b1h = wp[2048 * 1 + fi];
                bf16x8 b1l = wp[6144 + 2048 * 1 + fi];
                bf16x8 b2h = wp[2048 * 2 + fi];
                bf16x8 b2l = wp[6144 + 2048 * 2 + fi];
                a1 = __builtin_amdgcn_mfma_f32_16x16x32_bf16(ah[kk], b1h, a1, 0, 0, 0);
                a1 = __builtin_amdgcn_mfma_f32_16x16x32_bf16(al[kk], b1h, a1, 0, 0, 0);
                a1 = __builtin_amdgcn_mfma_f32_16x16x32_bf16(ah[kk], b1l, a1, 0, 0, 0);
                a2 = __builtin_amdgcn_mfma_f32_16x16x32_bf16(ah[kk], b2h, a2, 0, 0, 0);
                a2 = __builtin_amdgcn_mfma_f32_16x16x32_bf16(al[kk], b2h, a2, 0, 0, 0);
                a2 = __builtin_amdgcn_mfma_f32_16x16x32_bf16(ah[kk], b2l, a2, 0, 0, 0);
            }
            int col = nt * 16 + (lane & 15);
#pragma unroll
            for (int reg = 0; reg < 4; ++reg) {
                int lrow = lrow0 + reg;
                int byte = (lrow * 256 + col * 2) ^ ((lrow & 7) << 4);
                float xv = bf2f(*(const unsigned short*)(xbh + byte))
                         + bf2f(*(const unsigned short*)(xbl + byte));
                p1[reg] = fmaf(a1[reg], xv, p1[reg]);
                p2[reg] = fmaf(a2[reg], xv, p2[reg]);
            }
        }
#pragma unroll
        for (int reg = 0; reg < 4; ++reg) {
#pragma unroll
            for (int off = 1; off < 16; off <<= 1) {
                p1[reg] += __shfl_xor(p1[reg], off);
                p2[reg] += __shfl_xor(p2[reg], off);
            }
        }
        if ((lane & 15) == 0) {
            int nbase = base + wave * 16 + (lane >> 4) * 4;
#pragma unroll
            for (int reg = 0; reg < 4; ++reg) {
                int node = nbase + reg;
                if (node < N_NODES) {
                    s1[node] = tanhf(p1[reg]);
                    s2[node] = tanhf(p2[reg]);
                }
            }
        }
    }
}

// ---------------- CSR build step 1: degree histogram (into cursor) ----------------
__global__ __launch_bounds__(256)
void degree_hist(const int* __restrict__ src, int* __restrict__ cursor) {
    int i = blockIdx.x * 256 + threadIdx.x;
    if (i < N_EDGES) atomicAdd(&cursor[src[i]], 1);
}

// ---------------- hierarchical scan, phase A: per-block sums ----------------
__global__ __launch_bounds__(256)
void scan_blocksum(const int* __restrict__ cursor, int* __restrict__ bsum) {
    __shared__ int red[256];
    const int b = blockIdx.x, t = threadIdx.x;
    const int base = b * SCAN_BC;
    int s = 0;
    for (int i = t; i < SCAN_BC; i += 256) s += cursor[base + i];
    red[t] = s;
    __syncthreads();
    for (int off = 128; off; off >>= 1) {
        if (t < off) red[t] += red[t + off];
        __syncthreads();
    }
    if (t == 0) bsum[b] = red[0];
}

// ---------------- phase B: exclusive scan of the 200 block sums ----------------
__global__ __launch_bounds__(256)
void scan_bases(int* __restrict__ bsum, int* __restrict__ row_off) {
    __shared__ int v[256];
    const int t = threadIdx.x;
    v[t] = (t < SCAN_NB) ? bsum[t] : 0;
    __syncthreads();
    for (int off = 1; off < 256; off <<= 1) {
        int u = (t >= off) ? v[t - off] : 0;
        __syncthreads();
        v[t] += u;
        __syncthreads();
    }
    if (t < SCAN_NB) bsum[t] = (t == 0) ? 0 : v[t - 1];
    if (t == 0) row_off[N_NODES] = v[SCAN_NB - 1];
}

// ---------------- phase C: per-block exclusive scan + write row_off/cursor ---------
__global__ __launch_bounds__(256)
void scan_write(int* __restrict__ cursor, const int* __restrict__ bsum,
                int* __restrict__ row_off) {
    __shared__ int tsum[256];
    const int b = blockIdx.x, t = threadIdx.x;
    const int i0 = b * SCAN_BC + t * 2;   // t < 250 covers the 500-elem chunk
    int d0 = 0, d1 = 0;
    if (t < 250) { d0 = cursor[i0]; d1 = cursor[i0 + 1]; }
    tsum[t] = d0 + d1;
    __syncthreads();
    for (int off = 1; off < 256; off <<= 1) {
        int u = (t >= off) ? tsum[t - off] : 0;
        __syncthreads();
        tsum[t] += u;
        __syncthreads();
    }
    if (t < 250) {
        int run = bsum[b] + ((t == 0) ? 0 : tsum[t - 1]);
        row_off[i0] = run; cursor[i0] = run; run += d0;
        row_off[i0 + 1] = run; cursor[i0 + 1] = run;
    }
}

// ---------------- CSR build step 3: scatter edges + compute leaky_relu score -------
__global__ __launch_bounds__(256)
void scatter_edges(const int* __restrict__ src, const int* __restrict__ dst,
                   const float* __restrict__ s1, const float* __restrict__ s2,
                   int* __restrict__ cursor,
                   int* __restrict__ dst_sorted, float* __restrict__ e_sorted) {
    int i = blockIdx.x * 256 + threadIdx.x;
    if (i >= N_EDGES) return;
    int s = src[i], d = dst[i];
    float v = s1[s] + s2[d];
    float e = v > 0.f ? v : 0.01f * v;
    int pos = atomicAdd(&cursor[s], 1);
    dst_sorted[pos] = d;
    e_sorted[pos] = e;
}

// ---------------- per-node: softmax + weighted gather-accumulate + relu ------------
__global__ __launch_bounds__(128)
void node_aggregate(const int* __restrict__ row_off, const int* __restrict__ dst_sorted,
                    const float* __restrict__ e_sorted, const float* __restrict__ mapped,
                    float* __restrict__ out) {
    const int n = blockIdx.x;
    const int c = threadIdx.x;
    const int beg = row_off[n], end = row_off[n + 1];
    float acc = 0.f;
    if (beg < end) {
        float m = -INFINITY;
        for (int j = beg; j < end; ++j) m = fmaxf(m, e_sorted[j]);  // broadcast loads
        float den = 0.f;
        __shared__ float ee[128];
        __shared__ int   dd[128];
        for (int chunk = beg; chunk < end; chunk += 128) {
            int nc = min(128, end - chunk);
            if (c < nc) {
                ee[c] = expf(e_sorted[chunk + c] - m);
                dd[c] = dst_sorted[chunk + c];
            }
            __syncthreads();
            for (int j = 0; j < nc; ++j) {
                float w = ee[j];
                den += w;
                acc = fmaf(w, mapped[(size_t)dd[j] * D + c], acc);
            }
            __syncthreads();
        }
        acc = acc / fmaxf(den, 1e-16f);
    }
    out[(size_t)n * D + c] = fmaxf(acc, 0.f);
}

extern "C" void kernel_launch(void* const* d_in, const int* in_sizes, int n_in,
                              void* d_out, int out_size, void* d_ws, size_t ws_size,
                              hipStream_t stream) {
    const float* x     = (const float*)d_in[0];
    const int*   ei    = (const int*)d_in[1];   // [2][E]: row0 = src, row1 = dst
    const float* k0    = (const float*)d_in[2];
    const float* k1    = (const float*)d_in[3];
    const float* k2    = (const float*)d_in[4];
    const float* gamma = (const float*)d_in[5];
    const float* beta  = (const float*)d_in[6];
    float* out = (float*)d_out;

    const int* src = ei;
    const int* dst = ei + N_EDGES;

    char* ws = (char*)d_ws;
    unsigned short* wpack = (unsigned short*)ws;           ws += 6 * 128 * 128 * 2; // hi+lo
    float* s1       = (float*)ws;                          ws += N_NODES * 4;
    float* s2       = (float*)ws;                          ws += N_NODES * 4;
    float* scale    = (float*)ws;                          ws += 128 * 4;
    float* bias     = (float*)ws;                          ws += 128 * 4;
    float* sums     = (float*)ws;                          ws += 256 * 4;
    int*   bsum     = (int*)ws;                            ws += 256 * 4;
    int*   row_off  = (int*)ws;                            ws += (N_NODES + 1) * 4;
    int*   cursor   = (int*)ws;                            ws += N_NODES * 4;
    int*   dst_sorted = (int*)ws;                          ws += (size_t)N_EDGES * 4;
    float* e_sorted   = (float*)ws;                        ws += (size_t)N_EDGES * 4;
    float* mapped     = (float*)ws;                        ws += (size_t)N_NODES * D * 4;

    // zero accumulators (harness does not re-poison between replays)
    hipMemsetAsync(sums, 0, 256 * sizeof(float), stream);
    hipMemsetAsync(cursor, 0, N_NODES * sizeof(int), stream);

    bn_stats<<<256, 256, 0, stream>>>(x, sums);
    bn_finalize<<<1, 128, 0, stream>>>(sums, gamma, beta, scale, bias);
    pack_weights<<<24, 256, 0, stream>>>(k0, k1, k2, wpack);
    gemm_mfma<<<(N_NODES + 63) / 64, 256, 0, stream>>>(x, wpack, scale, bias,
                                                       mapped, s1, s2);
    degree_hist<<<N_EDGES / 256, 256, 0, stream>>>(src, cursor);
    scan_blocksum<<<SCAN_NB, 256, 0, stream>>>(cursor, bsum);
    scan_bases<<<1, 256, 0, stream>>>(bsum, row_off);
    scan_write<<<SCAN_NB, 256, 0, stream>>>(cursor, bsum, row_off);
    scatter_edges<<<N_EDGES / 256, 256, 0, stream>>>(src, dst, s1, s2, cursor,
                                                     dst_sorted, e_sorted);
    node_aggregate<<<N_NODES, 128, 0, stream>>>(row_off, dst_sorted, e_sorted,
                                                mapped, out);
}

// Round 6
// 433.907 us; speedup vs baseline: 2.5658x; 1.0978x over previous
//
#include <hip/hip_runtime.h>
#include <math.h>

#define N_NODES 100000
#define D 128
#define N_EDGES 1600000
#define BN_EPS 1e-5f
#define SCAN_NB 200
#define SCAN_BC 500   // elements per scan block; 200*500 = 100000 exact

typedef __attribute__((ext_vector_type(8))) short bf16x8;
typedef __attribute__((ext_vector_type(4))) float f32x4;

__device__ inline unsigned short f2bf(float f) {
    unsigned int u = __float_as_uint(f);
    unsigned int r = u + 0x7FFFu + ((u >> 16) & 1u);
    return (unsigned short)(r >> 16);
}
__device__ inline float bf2f(unsigned short b) {
    return __uint_as_float(((unsigned int)b) << 16);
}

// ---------------- BN column stats: sum and sumsq per column ----------------
__global__ __launch_bounds__(256)
void bn_stats(const float* __restrict__ x, float* __restrict__ sums) {
    const int col  = threadIdx.x & 127;
    const int half = threadIdx.x >> 7;
    float s = 0.f, sq = 0.f;
    for (int r = blockIdx.x * 2 + half; r < N_NODES; r += gridDim.x * 2) {
        float v = x[(size_t)r * D + col];
        s += v; sq += v * v;
    }
    __shared__ float ls[2][128];
    __shared__ float lq[2][128];
    ls[half][col] = s; lq[half][col] = sq;
    __syncthreads();
    if (threadIdx.x < 128) {
        atomicAdd(&sums[col],       ls[0][col] + ls[1][col]);
        atomicAdd(&sums[128 + col], lq[0][col] + lq[1][col]);
    }
}

// ---------------- fold BN into per-column scale/bias ----------------
__global__ void bn_finalize(const float* __restrict__ sums,
                            const float* __restrict__ gamma,
                            const float* __restrict__ beta,
                            float* __restrict__ scale, float* __restrict__ bias) {
    int c = threadIdx.x;
    float mean = sums[c] * (1.0f / N_NODES);
    float var  = sums[128 + c] * (1.0f / N_NODES) - mean * mean;
    float rstd = rsqrtf(var + BN_EPS);
    float sc = gamma[c] * rstd;
    scale[c] = sc;
    bias[c]  = beta[c] - mean * sc;
}

// ---------------- pack 3 weight matrices into bf16 B-fragment order (hi + lo) ------
// frag id = (m*32 + kk*8 + nt); element: k = kk*32 + (lane>>4)*8 + i, col = nt*16 + (lane&15)
// hi frags at [0, 6144), lo frags at [6144, 12288)
__global__ __launch_bounds__(256)
void pack_weights(const float* __restrict__ k0, const float* __restrict__ k1,
                  const float* __restrict__ k2, unsigned short* __restrict__ wpack) {
    int idx = blockIdx.x * 256 + threadIdx.x;     // one 8-elem fragment per thread
    if (idx >= 3 * 4 * 8 * 64) return;            // 6144
    int m    = idx >> 11;
    int r    = idx & 2047;
    int kk   = r >> 9;
    int r2   = r & 511;
    int nt   = r2 >> 6;
    int lane = r2 & 63;
    const float* W = (m == 0) ? k0 : (m == 1) ? k1 : k2;
    int col   = nt * 16 + (lane & 15);
    int kbase = kk * 32 + (lane >> 4) * 8;
    unsigned int wh[4], wl[4];
#pragma unroll
    for (int i = 0; i < 4; ++i) {
        float a = W[(kbase + 2 * i)     * 128 + col];
        float b = W[(kbase + 2 * i + 1) * 128 + col];
        unsigned short ah = f2bf(a), bh = f2bf(b);
        unsigned short al = f2bf(a - bf2f(ah)), bl = f2bf(b - bf2f(bh));
        wh[i] = (unsigned int)ah | ((unsigned int)bh << 16);
        wl[i] = (unsigned int)al | ((unsigned int)bl << 16);
    }
    uint4* outp = (uint4*)wpack;
    outp[idx]        = make_uint4(wh[0], wh[1], wh[2], wh[3]);
    outp[6144 + idx] = make_uint4(wl[0], wl[1], wl[2], wl[3]);
}

// ---------------- MFMA: xn = BN(x); mapped = xn@K0; s1/s2 = tanh((xn@K{1,2}).xn) ----
// mapped: bf16 output (halves the gather traffic in node_aggregate).
// s1/s2: split-precision (hi+lo) — bf16-only gave z-err ~0.04 -> FAIL R4.
__global__ __launch_bounds__(256)
void gemm_mfma(const float* __restrict__ x, const unsigned short* __restrict__ wpack,
               const float* __restrict__ scale, const float* __restrict__ bias,
               unsigned short* __restrict__ mapped, float* __restrict__ s1,
               float* __restrict__ s2) {
    const int tid  = threadIdx.x;
    const int wave = tid >> 6, lane = tid & 63;
    const int base = blockIdx.x * 64;
    __shared__ unsigned short xhi[64 * 128];   // 16 KB bf16, XOR-swizzled rows
    __shared__ unsigned short xlo[64 * 128];   // 16 KB bf16 residual
    char* xbh = (char*)xhi;
    char* xbl = (char*)xlo;

    // ---- stage xn (BN applied) into LDS as bf16 hi+lo, swizzled ----
    float2 sc = ((const float2*)scale)[lane];
    float2 bs = ((const float2*)bias)[lane];
    for (int rr = 0; rr < 16; ++rr) {
        int row  = wave * 16 + rr;
        int node = base + row;
        float2 v = make_float2(0.f, 0.f);
        if (node < N_NODES) v = ((const float2*)x)[(size_t)node * 64 + lane];
        float f0 = v.x * sc.x + bs.x;
        float f1 = v.y * sc.y + bs.y;
        unsigned short h0 = f2bf(f0), h1 = f2bf(f1);
        unsigned short l0 = f2bf(f0 - bf2f(h0)), l1 = f2bf(f1 - bf2f(h1));
        int byte = (row * 256 + lane * 4) ^ ((row & 7) << 4);
        *(unsigned int*)(xbh + byte) = (unsigned int)h0 | ((unsigned int)h1 << 16);
        *(unsigned int*)(xbl + byte) = (unsigned int)l0 | ((unsigned int)l1 << 16);
    }
    __syncthreads();

    // ---- A fragments (row = lane&15, k = (lane>>4)*8 + i) ----
    bf16x8 ah[4], al[4];
    {
        int arow = wave * 16 + (lane & 15);
#pragma unroll
        for (int kk = 0; kk < 4; ++kk) {
            int byte = (arow * 256 + kk * 64 + (lane >> 4) * 16) ^ ((arow & 7) << 4);
            ah[kk] = *(const bf16x8*)(xbh + byte);
            al[kk] = *(const bf16x8*)(xbl + byte);
        }
    }
    const bf16x8* wp = (const bf16x8*)wpack;   // hi: [0,6144) frags; lo: +6144

    // ---- matrix 0 -> mapped (hi-only precision, bf16 store) ----
    {
        f32x4 acc[8] = {};
#pragma unroll
        for (int kk = 0; kk < 4; ++kk) {
#pragma unroll
            for (int nt = 0; nt < 8; ++nt) {
                bf16x8 b = wp[(kk * 8 + nt) * 64 + lane];
                acc[nt] = __builtin_amdgcn_mfma_f32_16x16x32_bf16(ah[kk], b, acc[nt], 0, 0, 0);
            }
        }
        int crow = base + wave * 16 + (lane >> 4) * 4;
        int ccol = lane & 15;
#pragma unroll
        for (int nt = 0; nt < 8; ++nt) {
#pragma unroll
            for (int reg = 0; reg < 4; ++reg) {
                int node = crow + reg;
                if (node < N_NODES)
                    mapped[(size_t)node * 128 + nt * 16 + ccol] = f2bf(acc[nt][reg]);
            }
        }
    }

    // ---- matrices 1,2 (split precision) -> per-row dot with xn -> s1,s2 ----
    {
        float p1[4] = {0.f, 0.f, 0.f, 0.f};
        float p2[4] = {0.f, 0.f, 0.f, 0.f};
        int lrow0 = wave * 16 + (lane >> 4) * 4;
#pragma unroll
        for (int nt = 0; nt < 8; ++nt) {
            f32x4 a1 = {0.f, 0.f, 0.f, 0.f};
            f32x4 a2 = {0.f, 0.f, 0.f, 0.f};
#pragma unroll
            for (int kk = 0; kk < 4; ++kk) {
                int fi = (kk * 8 + nt) * 64 + lane;
                bf16x8 b1h = wp[2048 * 1 + fi];
                bf16x8 b1l = wp[6144 + 2048 * 1 + fi];
                bf16x8 b2h = wp[2048 * 2 + fi];
                bf16x8 b2l = wp[6144 + 2048 * 2 + fi];
                a1 = __builtin_amdgcn_mfma_f32_16x16x32_bf16(ah[kk], b1h, a1, 0, 0, 0);
                a1 = __builtin_amdgcn_mfma_f32_16x16x32_bf16(al[kk], b1h, a1, 0, 0, 0);
                a1 = __builtin_amdgcn_mfma_f32_16x16x32_bf16(ah[kk], b1l, a1, 0, 0, 0);
                a2 = __builtin_amdgcn_mfma_f32_16x16x32_bf16(ah[kk], b2h, a2, 0, 0, 0);
                a2 = __builtin_amdgcn_mfma_f32_16x16x32_bf16(al[kk], b2h, a2, 0, 0, 0);
                a2 = __builtin_amdgcn_mfma_f32_16x16x32_bf16(ah[kk], b2l, a2, 0, 0, 0);
            }
            int col = nt * 16 + (lane & 15);
#pragma unroll
            for (int reg = 0; reg < 4; ++reg) {
                int lrow = lrow0 + reg;
                int byte = (lrow * 256 + col * 2) ^ ((lrow & 7) << 4);
                float xv = bf2f(*(const unsigned short*)(xbh + byte))
                         + bf2f(*(const unsigned short*)(xbl + byte));
                p1[reg] = fmaf(a1[reg], xv, p1[reg]);
                p2[reg] = fmaf(a2[reg], xv, p2[reg]);
            }
        }
#pragma unroll
        for (int reg = 0; reg < 4; ++reg) {
#pragma unroll
            for (int off = 1; off < 16; off <<= 1) {
                p1[reg] += __shfl_xor(p1[reg], off);
                p2[reg] += __shfl_xor(p2[reg], off);
            }
        }
        if ((lane & 15) == 0) {
            int nbase = base + wave * 16 + (lane >> 4) * 4;
#pragma unroll
            for (int reg = 0; reg < 4; ++reg) {
                int node = nbase + reg;
                if (node < N_NODES) {
                    s1[node] = tanhf(p1[reg]);
                    s2[node] = tanhf(p2[reg]);
                }
            }
        }
    }
}

// ---------------- CSR build step 1: degree histogram (into cursor) ----------------
__global__ __launch_bounds__(256)
void degree_hist(const int* __restrict__ src, int* __restrict__ cursor) {
    int i = blockIdx.x * 256 + threadIdx.x;
    if (i < N_EDGES) atomicAdd(&cursor[src[i]], 1);
}

// ---------------- hierarchical scan, phase A: per-block sums ----------------
__global__ __launch_bounds__(256)
void scan_blocksum(const int* __restrict__ cursor, int* __restrict__ bsum) {
    __shared__ int red[256];
    const int b = blockIdx.x, t = threadIdx.x;
    const int base = b * SCAN_BC;
    int s = 0;
    for (int i = t; i < SCAN_BC; i += 256) s += cursor[base + i];
    red[t] = s;
    __syncthreads();
    for (int off = 128; off; off >>= 1) {
        if (t < off) red[t] += red[t + off];
        __syncthreads();
    }
    if (t == 0) bsum[b] = red[0];
}

// ---------------- phase B: exclusive scan of the 200 block sums ----------------
__global__ __launch_bounds__(256)
void scan_bases(int* __restrict__ bsum, int* __restrict__ row_off) {
    __shared__ int v[256];
    const int t = threadIdx.x;
    v[t] = (t < SCAN_NB) ? bsum[t] : 0;
    __syncthreads();
    for (int off = 1; off < 256; off <<= 1) {
        int u = (t >= off) ? v[t - off] : 0;
        __syncthreads();
        v[t] += u;
        __syncthreads();
    }
    if (t < SCAN_NB) bsum[t] = (t == 0) ? 0 : v[t - 1];
    if (t == 0) row_off[N_NODES] = v[SCAN_NB - 1];
}

// ---------------- phase C: per-block exclusive scan + write row_off/cursor ---------
__global__ __launch_bounds__(256)
void scan_write(int* __restrict__ cursor, const int* __restrict__ bsum,
                int* __restrict__ row_off) {
    __shared__ int tsum[256];
    const int b = blockIdx.x, t = threadIdx.x;
    const int i0 = b * SCAN_BC + t * 2;   // t < 250 covers the 500-elem chunk
    int d0 = 0, d1 = 0;
    if (t < 250) { d0 = cursor[i0]; d1 = cursor[i0 + 1]; }
    tsum[t] = d0 + d1;
    __syncthreads();
    for (int off = 1; off < 256; off <<= 1) {
        int u = (t >= off) ? tsum[t - off] : 0;
        __syncthreads();
        tsum[t] += u;
        __syncthreads();
    }
    if (t < 250) {
        int run = bsum[b] + ((t == 0) ? 0 : tsum[t - 1]);
        row_off[i0] = run; cursor[i0] = run; run += d0;
        row_off[i0 + 1] = run; cursor[i0 + 1] = run;
    }
}

// ---------------- CSR build step 3: scatter edges + compute leaky_relu score -------
__global__ __launch_bounds__(256)
void scatter_edges(const int* __restrict__ src, const int* __restrict__ dst,
                   const float* __restrict__ s1, const float* __restrict__ s2,
                   int* __restrict__ cursor,
                   int* __restrict__ dst_sorted, float* __restrict__ e_sorted) {
    int i = blockIdx.x * 256 + threadIdx.x;
    if (i >= N_EDGES) return;
    int s = src[i], d = dst[i];
    float v = s1[s] + s2[d];
    float e = v > 0.f ? v : 0.01f * v;
    int pos = atomicAdd(&cursor[s], 1);
    dst_sorted[pos] = d;
    e_sorted[pos] = e;
}

// ---------------- per-node (1 wave each): softmax + weighted gather + relu --------
// mapped is bf16: one uint per lane = 2 columns; row gather = 64 lanes x 4 B.
__global__ __launch_bounds__(256)
void node_aggregate(const int* __restrict__ row_off, const int* __restrict__ dst_sorted,
                    const float* __restrict__ e_sorted,
                    const unsigned int* __restrict__ mapped,
                    float* __restrict__ out) {
    const int wave = threadIdx.x >> 6, lane = threadIdx.x & 63;
    const int n = blockIdx.x * 4 + wave;
    if (n >= N_NODES) return;
    const int beg = row_off[n], end = row_off[n + 1];
    float acc0 = 0.f, acc1 = 0.f, den = 0.f;
    if (beg < end) {
        // lane-parallel segment max
        float m = -INFINITY;
        for (int j = beg + lane; j < end; j += 64) m = fmaxf(m, e_sorted[j]);
#pragma unroll
        for (int off = 1; off < 64; off <<= 1) m = fmaxf(m, __shfl_xor(m, off));
        // chunks of 64 edges: exp + in-register broadcast via shfl
        for (int chunk = beg; chunk < end; chunk += 64) {
            int nc = min(64, end - chunk);
            float w_l = 0.f;
            int   d_l = 0;
            if (lane < nc) {
                w_l = expf(e_sorted[chunk + lane] - m);
                d_l = dst_sorted[chunk + lane];
            }
            den += w_l;
            for (int j = 0; j < nc; ++j) {
                float wj = __shfl(w_l, j);
                int   dj = __shfl(d_l, j);
                unsigned int mv = mapped[(size_t)dj * 64 + lane];
                acc0 = fmaf(wj, bf2f((unsigned short)(mv & 0xFFFFu)), acc0);
                acc1 = fmaf(wj, bf2f((unsigned short)(mv >> 16)), acc1);
            }
        }
#pragma unroll
        for (int off = 1; off < 64; off <<= 1) den += __shfl_xor(den, off);
        float inv = 1.f / fmaxf(den, 1e-16f);
        acc0 *= inv; acc1 *= inv;
    }
    ((float2*)out)[(size_t)n * 64 + lane] = make_float2(fmaxf(acc0, 0.f), fmaxf(acc1, 0.f));
}

extern "C" void kernel_launch(void* const* d_in, const int* in_sizes, int n_in,
                              void* d_out, int out_size, void* d_ws, size_t ws_size,
                              hipStream_t stream) {
    const float* x     = (const float*)d_in[0];
    const int*   ei    = (const int*)d_in[1];   // [2][E]: row0 = src, row1 = dst
    const float* k0    = (const float*)d_in[2];
    const float* k1    = (const float*)d_in[3];
    const float* k2    = (const float*)d_in[4];
    const float* gamma = (const float*)d_in[5];
    const float* beta  = (const float*)d_in[6];
    float* out = (float*)d_out;

    const int* src = ei;
    const int* dst = ei + N_EDGES;

    char* ws = (char*)d_ws;
    unsigned short* wpack = (unsigned short*)ws;           ws += 6 * 128 * 128 * 2; // hi+lo
    float* s1       = (float*)ws;                          ws += N_NODES * 4;
    float* s2       = (float*)ws;                          ws += N_NODES * 4;
    float* scale    = (float*)ws;                          ws += 128 * 4;
    float* bias     = (float*)ws;                          ws += 128 * 4;
    float* sums     = (float*)ws;                          ws += 256 * 4;
    int*   bsum     = (int*)ws;                            ws += 256 * 4;
    int*   row_off  = (int*)ws;                            ws += (N_NODES + 1) * 4;
    int*   cursor   = (int*)ws;                            ws += N_NODES * 4;
    int*   dst_sorted = (int*)ws;                          ws += (size_t)N_EDGES * 4;
    float* e_sorted   = (float*)ws;                        ws += (size_t)N_EDGES * 4;
    unsigned short* mapped = (unsigned short*)ws;          ws += (size_t)N_NODES * D * 2;

    // zero accumulators (harness does not re-poison between replays)
    hipMemsetAsync(sums, 0, 256 * sizeof(float), stream);
    hipMemsetAsync(cursor, 0, N_NODES * sizeof(int), stream);

    bn_stats<<<256, 256, 0, stream>>>(x, sums);
    bn_finalize<<<1, 128, 0, stream>>>(sums, gamma, beta, scale, bias);
    pack_weights<<<24, 256, 0, stream>>>(k0, k1, k2, wpack);
    gemm_mfma<<<(N_NODES + 63) / 64, 256, 0, stream>>>(x, wpack, scale, bias,
                                                       mapped, s1, s2);
    degree_hist<<<N_EDGES / 256, 256, 0, stream>>>(src, cursor);
    scan_blocksum<<<SCAN_NB, 256, 0, stream>>>(cursor, bsum);
    scan_bases<<<1, 256, 0, stream>>>(bsum, row_off);
    scan_write<<<SCAN_NB, 256, 0, stream>>>(cursor, bsum, row_off);
    scatter_edges<<<N_EDGES / 256, 256, 0, stream>>>(src, dst, s1, s2, cursor,
                                                     dst_sorted, e_sorted);
    node_aggregate<<<(N_NODES + 3) / 4, 256, 0, stream>>>(row_off, dst_sorted,
                                                          e_sorted,
                                                          (const unsigned int*)mapped,
                                                          out);
}